// Round 8
// baseline (192.849 us; speedup 1.0000x reference)
//
#include <hip/hip_runtime.h>
#include <math.h>

#define B_ 8
#define M_ 10
#define S_ 200
#define PADS_ 208            // S padded to multiple of 16 (sentinel points)
#define N_ 2048
#define L_ 128
#define BETA_ 0.01f
#define EPS_ 1e-6f
#define INF_U 0x7F7F7F7Fu
#define SENT_ 5.0e18f        // sentinel coord; |p|^2 = 7.5e37, finite, never wins min

#define NT_ 128                           // n per block
#define TILES_ (N_ / NT_)                 // 16
#define NBLK_ (B_ * M_ * TILES_)          // 1280

__device__ __forceinline__ float fexp_(float x, float p) {
    float s = (x > 0.f) ? 1.f : ((x < 0.f) ? -1.f : 0.f);
    return s * powf(fmaxf(fabsf(x), EPS_), p);
}

// ---------------------------------------------------------------------------
// Single fused kernel. Block = (bm, tile). 1280 blocks x 256.
//   Stage (in-block, no prep dispatch): R (t==0), pts[208] w/ |p|^2 (t<208),
//     rotated n-points as (A=-2X, c2=|X|^2) (t<128).
//   Main loop: sg=lane&15 owns 13 s; ng=wave*4+(lane>>4) owns 8 n.
//     1 ds_read_b128 + 8 evals (4 fma-ish + 2 min) per iter.
//   V: shfl over lane bits 0..3 -> sV -> coalesced store vpart[bm][n].
//   smin: 2 shfl + LDS atomicMin -> pure store spart[bm][tile][s].
//   Merge roles (opportunistic last-arriver, counters survive graph replay
//   via mod detection; release/acquire via __threadfence, G16):
//     A: last of 16 tiles per bm:     dmp[bm]  = sum_s min_tile spart
//     B: last of 10 m per (b,tile):   pclpart[b][tile] = sum_n Fs.Vs
//     C: last of all 1280:            KLD + combine -> out[4]
//   No float atomics anywhere -> deterministic FP order.
// ---------------------------------------------------------------------------
__global__ __launch_bounds__(256) void fused_all(
    const float* __restrict__ ipts,  const float* __restrict__ trans,
    const float* __restrict__ rot,   const float* __restrict__ psize,
    const float* __restrict__ shp,   const float* __restrict__ def,
    const float* __restrict__ probs, const float* __restrict__ etas,
    const float* __restrict__ omegas,const float* __restrict__ mu,
    const float* __restrict__ logvar,
    float* __restrict__ vpart, float* __restrict__ spart,
    float* __restrict__ pclpart, float* __restrict__ dmp,
    unsigned int* __restrict__ cntBM, unsigned int* __restrict__ cntBT,
    unsigned int* __restrict__ gcnt, float* __restrict__ out)
{
    __shared__ float4 sPts[PADS_];          // 3328 B
    __shared__ float4 sXt[NT_];             // 2048 B  (A0,A1,A2,c2)
    __shared__ unsigned int sMinS[PADS_];   // 832 B
    __shared__ float sV[NT_];               // 512 B
    __shared__ float sR[9];
    __shared__ float sRed[12];
    __shared__ int sFlagA, sFlagB, sFlagC;

    const int t    = threadIdx.x;
    const int tile = blockIdx.x % TILES_;
    const int bm   = blockIdx.x / TILES_;
    const int b    = bm / M_;
    const int lane = t & 63, wave = t >> 6;

    // ---- staging: R + pts (trig) ----
    if (t == 0) {
        float w = rot[bm*4+0], x = rot[bm*4+1], y = rot[bm*4+2], z = rot[bm*4+3];
        float inv = 1.f / sqrtf(w*w + x*x + y*y + z*z);
        w *= inv; x *= inv; y *= inv; z *= inv;
        sR[0] = 1.f - 2.f*(y*y + z*z); sR[1] = 2.f*(x*y - w*z);       sR[2] = 2.f*(x*z + w*y);
        sR[3] = 2.f*(x*y + w*z);       sR[4] = 1.f - 2.f*(x*x + z*z); sR[5] = 2.f*(y*z - w*x);
        sR[6] = 2.f*(x*z - w*y);       sR[7] = 2.f*(y*z + w*x);       sR[8] = 1.f - 2.f*(x*x + y*y);
    }
    if (t < PADS_) {
        sMinS[t] = INF_U;
        if (t < S_) {
            float a1 = psize[bm*3+0], a2 = psize[bm*3+1], a3 = psize[bm*3+2];
            float e1 = shp[bm*2+0],  e2 = shp[bm*2+1];
            float d0 = def[bm*2+0],  d1 = def[bm*2+1];
            float eta = etas[bm*S_+t], om = omegas[bm*S_+t];
            float ce = cosf(eta), se = sinf(eta);
            float co = cosf(om),  so = sinf(om);
            float fce = fexp_(ce, e1), fse = fexp_(se, e1);
            float fco = fexp_(co, e2), fso = fexp_(so, e2);
            float px = a1 * fce * fco;
            float py = a2 * fce * fso;
            float pz = a3 * fse;
            float fr = pz / a3;
            px *= d0*fr + 1.f;
            py *= d1*fr + 1.f;
            sPts[t] = make_float4(px, py, pz, px*px + py*py + pz*pz);
        } else {
            sPts[t] = make_float4(SENT_, SENT_, SENT_, 3.f*SENT_*SENT_);
        }
    }
    __syncthreads();

    if (t < NT_) {
        int n = tile*NT_ + t;
        const float* ip = ipts + (size_t)(b*N_ + n)*3;
        float cx = ip[0] - trans[bm*3+0];
        float cy = ip[1] - trans[bm*3+1];
        float cz = ip[2] - trans[bm*3+2];
        float X0 = sR[0]*cx + sR[1]*cy + sR[2]*cz;
        float X1 = sR[3]*cx + sR[4]*cy + sR[5]*cz;
        float X2 = sR[6]*cx + sR[7]*cy + sR[8]*cz;
        sXt[t] = make_float4(-2.f*X0, -2.f*X1, -2.f*X2, X0*X0 + X1*X1 + X2*X2);
    }
    __syncthreads();

    // ---- main dist loop ----
    const int sg = lane & 15;                // s-group (lane bits 0..3)
    const int ng = wave*4 + (lane >> 4);     // n-group 0..15, owns n = ng*8+j

    float4 A[8];
    #pragma unroll
    for (int j = 0; j < 8; ++j) A[j] = sXt[ng*8 + j];   // broadcast reads

    float vmin[8];
    #pragma unroll
    for (int j = 0; j < 8; ++j) vmin[j] = 3.4e38f;

    #pragma unroll 4
    for (int k = 0; k < 13; ++k) {
        float4 p = sPts[k*16 + sg];          // 16 consecutive float4: free 2-way
        float dm = 3.4e38f;
        #pragma unroll
        for (int j = 0; j < 8; ++j) {
            float d = fmaf(p.x, A[j].x,
                      fmaf(p.y, A[j].y,
                      fmaf(p.z, A[j].z, p.w + A[j].w)));
            vmin[j] = fminf(vmin[j], d);
            dm = fminf(dm, d);
        }
        dm = fminf(dm, __shfl_xor(dm, 16));
        dm = fminf(dm, __shfl_xor(dm, 32));
        if (lane < 16) atomicMin(&sMinS[k*16 + sg], __float_as_uint(dm));
    }

    // V: min over the 16 s-groups (lane bits 0..3)
    #pragma unroll
    for (int j = 0; j < 8; ++j) {
        float v = vmin[j];
        #pragma unroll
        for (int o = 1; o < 16; o <<= 1) v = fminf(v, __shfl_xor(v, o));
        vmin[j] = v;
    }
    if (sg == 0) {
        #pragma unroll
        for (int j = 0; j < 8; ++j) sV[ng*8 + j] = vmin[j];
    }
    __syncthreads();                         // sV + sMinS complete

    if (t < NT_) vpart[bm*N_ + tile*NT_ + t] = sV[t];
    if (t < S_)  spart[(size_t)(bm*TILES_ + tile)*S_ + t] = __uint_as_float(sMinS[t]);

    // ---- merge role detection (release fence, then counters) ----
    __threadfence();
    if (t == 0) {
        unsigned int oa = atomicAdd(&cntBM[bm], 1u);
        sFlagA = ((oa % TILES_) == TILES_ - 1);
        unsigned int ob = atomicAdd(&cntBT[b*TILES_ + tile], 1u);
        sFlagB = ((ob % M_) == M_ - 1);
    }
    __syncthreads();
    if (sFlagA || sFlagB) __threadfence();   // acquire (block-uniform branch)

    // ---- role A: dmp[bm] = sum_s min_tile spart[bm][tile][s] ----
    if (sFlagA) {
        float v = 0.f;
        if (t < S_) {
            const float* sp = spart + (size_t)bm*TILES_*S_ + t;
            float mn = 3.4e38f;
            #pragma unroll
            for (int tl = 0; tl < TILES_; ++tl) mn = fminf(mn, sp[tl*S_]);
            v = mn;
        }
        #pragma unroll
        for (int o = 1; o < 64; o <<= 1) v += __shfl_xor(v, o);
        if (lane == 0) sRed[wave] = v;
        __syncthreads();
        if (t == 0) dmp[bm] = sRed[0] + sRed[1] + sRed[2] + sRed[3];
        __syncthreads();                     // protect sRed for role B
    }

    // ---- role B: pclpart[b][tile] = sum over 128 n of sorted Fs.Vs ----
    if (sFlagB) {
        float sum = 0.f;
        if (t < NT_) {
            int n = tile*NT_ + t;
            float V[M_], P[M_];
            #pragma unroll
            for (int m = 0; m < M_; ++m) {
                V[m] = vpart[(b*M_ + m)*N_ + n];
                P[m] = probs[b*M_ + m];
            }
            #pragma unroll
            for (int i = 0; i < M_-1; ++i)
                #pragma unroll
                for (int j = 0; j < M_-1-i; ++j)
                    if (V[j] > V[j+1]) {
                        float tv = V[j]; V[j] = V[j+1]; V[j+1] = tv;
                        float tp = P[j]; P[j] = P[j+1]; P[j+1] = tp;
                    }
            float cum = 1.f;
            #pragma unroll
            for (int i = 0; i < M_; ++i) { sum += P[i] * cum * V[i]; cum *= (1.f - P[i]); }
        }
        #pragma unroll
        for (int o = 1; o < 64; o <<= 1) sum += __shfl_xor(sum, o);
        if (lane == 0) sRed[wave] = sum;
        __syncthreads();
        if (t == 0) pclpart[b*TILES_ + tile] = sRed[0] + sRed[1] + sRed[2] + sRed[3];
    }

    // ---- role C: final combine ----
    __threadfence();
    if (t == 0) {
        unsigned int oc = atomicAdd(gcnt, 1u);
        sFlagC = ((oc % NBLK_) == NBLK_ - 1);
    }
    __syncthreads();
    if (sFlagC) {
        __threadfence();                     // acquire
        float s0 = (t < B_*TILES_) ? pclpart[t] : 0.f;        // 128
        float s1 = (t < B_*M_)     ? dmp[t] * probs[t] : 0.f; // 80
        float s2 = 0.f;
        for (int i = t; i < B_*L_; i += 256) {
            float muv = mu[i], lv = logvar[i];
            s2 += -0.5f * (1.f + lv - muv*muv - expf(lv));
        }
        #pragma unroll
        for (int o = 1; o < 64; o <<= 1) {
            s0 += __shfl_xor(s0, o);
            s1 += __shfl_xor(s1, o);
            s2 += __shfl_xor(s2, o);
        }
        if (lane == 0) { sRed[wave] = s0; sRed[4+wave] = s1; sRed[8+wave] = s2; }
        __syncthreads();
        if (t == 0) {
            float S0 = sRed[0] + sRed[1] + sRed[2] + sRed[3];
            float S1 = sRed[4] + sRed[5] + sRed[6] + sRed[7];
            float S2 = sRed[8] + sRed[9] + sRed[10] + sRed[11];
            float pcl_to_prim = S0 / (float)(B_ * N_);
            float prim_to_pcl = S1 / (float)(B_ * S_);
            float kld = S2 / (float)B_;
            float prims = pcl_to_prim + prim_to_pcl;
            out[0] = prims + BETA_ * kld;   // total
            out[1] = prims;
            out[2] = 0.f;                   // regs
            out[3] = kld;
        }
    }
}

extern "C" void kernel_launch(void* const* d_in, const int* in_sizes, int n_in,
                              void* d_out, int out_size, void* d_ws, size_t ws_size,
                              hipStream_t stream) {
    const float* ipts    = (const float*)d_in[0];
    const float* trans   = (const float*)d_in[1];
    const float* rot     = (const float*)d_in[2];
    const float* psize   = (const float*)d_in[3];
    const float* shp     = (const float*)d_in[4];
    const float* def     = (const float*)d_in[5];
    const float* probs   = (const float*)d_in[6];
    const float* etas    = (const float*)d_in[7];
    const float* omegas  = (const float*)d_in[8];
    const float* mu      = (const float*)d_in[9];
    const float* logvar  = (const float*)d_in[10];
    float* out = (float*)d_out;

    char* ws = (char*)d_ws;
    float* vpart   = (float*)(ws);                   // B*M*N*4          = 655360
    float* spart   = (float*)(ws + 655360);          // B*M*TILES*S*4    = 1024000
    float* pclpart = (float*)(ws + 1679360);         // B*TILES*4        = 512
    float* dmp     = (float*)(ws + 1679872);         // B*M*4            = 320
    unsigned int* cntBM = (unsigned int*)(ws + 1680256); // 80*4 = 320
    unsigned int* cntBT = (unsigned int*)(ws + 1680640); // 128*4 = 512
    unsigned int* gcnt  = (unsigned int*)(ws + 1681216); // 4
    // counters are never reset: last-arriver detection uses modulo, which is
    // invariant to the (poisoned / accumulated) starting value.

    fused_all<<<NBLK_, 256, 0, stream>>>(ipts, trans, rot, psize, shp, def,
                                         probs, etas, omegas, mu, logvar,
                                         vpart, spart, pclpart, dmp,
                                         cntBM, cntBT, gcnt, out);
}

// Round 9
// 26.796 us; speedup vs baseline: 7.1968x; 7.1968x over previous
//
#include <hip/hip_runtime.h>
#include <math.h>

#define B_ 8
#define M_ 10
#define S_ 200
#define PADS_ 208            // S padded to multiple of 16 (sentinel points)
#define N_ 2048
#define L_ 128
#define BETA_ 0.01f
#define EPS_ 1e-6f
#define INF_U 0x7F7F7F7Fu
#define SENT_ 5.0e18f        // sentinel coord; |p|^2 = 7.5e37, finite, never wins min

#define NT_ 128                           // n per block
#define TILES_ (N_ / NT_)                 // 16
#define DIST_BLOCKS (B_ * M_ * TILES_)    // 1280
#define VS_BLOCKS ((B_ * N_) / 256)       // 64
#define MID_BLOCKS (VS_BLOCKS + B_*M_)    // 144

__device__ __forceinline__ float fexp_(float x, float p) {
    float s = (x > 0.f) ? 1.f : ((x < 0.f) ? -1.f : 0.f);
    return s * powf(fmaxf(fabsf(x), EPS_), p);
}

// ---------------------------------------------------------------------------
// dist_k: block = (bm, tile of 128 n). In-block staging (no prep dispatch):
//   R (t==0), pts[208] w/ |p|^2 (t<208, trig), rotated n as (A=-2X, |X|^2).
//   Main: sg=lane&15 owns 13 s; ng=wave*4+(lane>>4) owns 8 n.
//   Outputs are PURE STORES (no init, no atomics, no cross-block reads —
//   R8's same-kernel merges hit XCD L2 non-coherence, absmax 0.5):
//     vpart[bm][n]        (V, min over all s — block owns all s)
//     spart[bm][tile][s]  (partial smin over this block's 128 n)
// ---------------------------------------------------------------------------
__global__ __launch_bounds__(256) void dist_k(
    const float* __restrict__ ipts,  const float* __restrict__ trans,
    const float* __restrict__ rot,   const float* __restrict__ psize,
    const float* __restrict__ shp,   const float* __restrict__ def,
    const float* __restrict__ etas,  const float* __restrict__ omegas,
    float* __restrict__ vpart, float* __restrict__ spart)
{
    __shared__ float4 sPts[PADS_];          // 3328 B
    __shared__ float4 sXt[NT_];             // 2048 B  (A0,A1,A2,c2)
    __shared__ unsigned int sMinS[PADS_];   // 832 B
    __shared__ float sV[NT_];               // 512 B
    __shared__ float sR[9];

    const int t    = threadIdx.x;
    const int tile = blockIdx.x % TILES_;
    const int bm   = blockIdx.x / TILES_;
    const int b    = bm / M_;
    const int lane = t & 63, wave = t >> 6;

    if (t == 0) {
        float w = rot[bm*4+0], x = rot[bm*4+1], y = rot[bm*4+2], z = rot[bm*4+3];
        float inv = 1.f / sqrtf(w*w + x*x + y*y + z*z);
        w *= inv; x *= inv; y *= inv; z *= inv;
        sR[0] = 1.f - 2.f*(y*y + z*z); sR[1] = 2.f*(x*y - w*z);       sR[2] = 2.f*(x*z + w*y);
        sR[3] = 2.f*(x*y + w*z);       sR[4] = 1.f - 2.f*(x*x + z*z); sR[5] = 2.f*(y*z - w*x);
        sR[6] = 2.f*(x*z - w*y);       sR[7] = 2.f*(y*z + w*x);       sR[8] = 1.f - 2.f*(x*x + y*y);
    }
    if (t < PADS_) {
        sMinS[t] = INF_U;
        if (t < S_) {
            float a1 = psize[bm*3+0], a2 = psize[bm*3+1], a3 = psize[bm*3+2];
            float e1 = shp[bm*2+0],  e2 = shp[bm*2+1];
            float d0 = def[bm*2+0],  d1 = def[bm*2+1];
            float eta = etas[bm*S_+t], om = omegas[bm*S_+t];
            float ce = cosf(eta), se = sinf(eta);
            float co = cosf(om),  so = sinf(om);
            float fce = fexp_(ce, e1), fse = fexp_(se, e1);
            float fco = fexp_(co, e2), fso = fexp_(so, e2);
            float px = a1 * fce * fco;
            float py = a2 * fce * fso;
            float pz = a3 * fse;
            float fr = pz / a3;
            px *= d0*fr + 1.f;
            py *= d1*fr + 1.f;
            sPts[t] = make_float4(px, py, pz, px*px + py*py + pz*pz);
        } else {
            sPts[t] = make_float4(SENT_, SENT_, SENT_, 3.f*SENT_*SENT_);
        }
    }
    __syncthreads();

    if (t < NT_) {
        int n = tile*NT_ + t;
        const float* ip = ipts + (size_t)(b*N_ + n)*3;
        float cx = ip[0] - trans[bm*3+0];
        float cy = ip[1] - trans[bm*3+1];
        float cz = ip[2] - trans[bm*3+2];
        float X0 = sR[0]*cx + sR[1]*cy + sR[2]*cz;
        float X1 = sR[3]*cx + sR[4]*cy + sR[5]*cz;
        float X2 = sR[6]*cx + sR[7]*cy + sR[8]*cz;
        sXt[t] = make_float4(-2.f*X0, -2.f*X1, -2.f*X2, X0*X0 + X1*X1 + X2*X2);
    }
    __syncthreads();

    const int sg = lane & 15;                // s-group (lane bits 0..3)
    const int ng = wave*4 + (lane >> 4);     // n-group 0..15, owns n = ng*8+j

    float4 A[8];
    #pragma unroll
    for (int j = 0; j < 8; ++j) A[j] = sXt[ng*8 + j];   // broadcast reads

    float vmin[8];
    #pragma unroll
    for (int j = 0; j < 8; ++j) vmin[j] = 3.4e38f;

    #pragma unroll 4
    for (int k = 0; k < 13; ++k) {
        float4 p = sPts[k*16 + sg];          // 16 consecutive float4: free 2-way
        float dm = 3.4e38f;
        #pragma unroll
        for (int j = 0; j < 8; ++j) {
            float d = fmaf(p.x, A[j].x,
                      fmaf(p.y, A[j].y,
                      fmaf(p.z, A[j].z, p.w + A[j].w)));
            vmin[j] = fminf(vmin[j], d);
            dm = fminf(dm, d);
        }
        dm = fminf(dm, __shfl_xor(dm, 16));
        dm = fminf(dm, __shfl_xor(dm, 32));
        if (lane < 16) atomicMin(&sMinS[k*16 + sg], __float_as_uint(dm));
    }

    // V: min over the 16 s-groups (lane bits 0..3)
    #pragma unroll
    for (int j = 0; j < 8; ++j) {
        float v = vmin[j];
        #pragma unroll
        for (int o = 1; o < 16; o <<= 1) v = fminf(v, __shfl_xor(v, o));
        vmin[j] = v;
    }
    if (sg == 0) {
        #pragma unroll
        for (int j = 0; j < 8; ++j) sV[ng*8 + j] = vmin[j];
    }
    __syncthreads();

    if (t < NT_) vpart[bm*N_ + tile*NT_ + t] = sV[t];
    if (t < S_)  spart[(size_t)(bm*TILES_ + tile)*S_ + t] = __uint_as_float(sMinS[t]);
}

// ---------------------------------------------------------------------------
// mid_k: 144 blocks, two roles (inputs all crossed a dispatch boundary).
//  bid < 64: vsort — per n: load V[10] (coalesced), sort, Fs weighting,
//            block-sum -> pclpart[bid] (pure store).
//  bid >= 64: bm = bid-64 — thread t<200: min over 16 tiles of spart,
//            block-sum over s -> dmpW[bm] = sum * probs[bm] (pure store).
// ---------------------------------------------------------------------------
__global__ __launch_bounds__(256) void mid_k(const float* __restrict__ vpart,
                                             const float* __restrict__ spart,
                                             const float* __restrict__ probs,
                                             float* __restrict__ pclpart,
                                             float* __restrict__ dmpW)
{
    __shared__ float sSum[4];
    int t = threadIdx.x, lane = t & 63, wave = t >> 6;

    if (blockIdx.x < VS_BLOCKS) {
        int g = blockIdx.x*256 + t;        // 0..B*N-1
        int b = g / N_, n = g % N_;
        float V[M_], P[M_];
        #pragma unroll
        for (int m = 0; m < M_; ++m) {
            V[m] = vpart[(b*M_ + m)*N_ + n];
            P[m] = probs[b*M_ + m];
        }
        #pragma unroll
        for (int i = 0; i < M_-1; ++i)
            #pragma unroll
            for (int j = 0; j < M_-1-i; ++j)
                if (V[j] > V[j+1]) {
                    float tv = V[j]; V[j] = V[j+1]; V[j+1] = tv;
                    float tp = P[j]; P[j] = P[j+1]; P[j+1] = tp;
                }
        float cum = 1.f, sum = 0.f;
        #pragma unroll
        for (int i = 0; i < M_; ++i) { sum += P[i] * cum * V[i]; cum *= (1.f - P[i]); }

        #pragma unroll
        for (int o = 1; o < 64; o <<= 1) sum += __shfl_xor(sum, o);
        if (lane == 0) sSum[wave] = sum;
        __syncthreads();
        if (t == 0) pclpart[blockIdx.x] = sSum[0] + sSum[1] + sSum[2] + sSum[3];
    } else {
        int bm = blockIdx.x - VS_BLOCKS;   // 0..79
        float v = 0.f;
        if (t < S_) {
            const float* sp = spart + (size_t)bm*TILES_*S_ + t;
            float mn = 3.4e38f;
            #pragma unroll
            for (int tl = 0; tl < TILES_; ++tl) mn = fminf(mn, sp[tl*S_]);
            v = mn;
        }
        #pragma unroll
        for (int o = 1; o < 64; o <<= 1) v += __shfl_xor(v, o);
        if (lane == 0) sSum[wave] = v;
        __syncthreads();
        if (t == 0) dmpW[bm] = (sSum[0] + sSum[1] + sSum[2] + sSum[3]) * probs[bm];
    }
}

// ---------------------------------------------------------------------------
// final_k: 1 block x 256 — sum 64 pcl partials + 80 dmp partials + KLD.
// Fixed-order reductions -> bit-deterministic.
// ---------------------------------------------------------------------------
__global__ __launch_bounds__(256) void final_k(const float* __restrict__ pclpart,
                                               const float* __restrict__ dmpW,
                                               const float* __restrict__ mu,
                                               const float* __restrict__ logvar,
                                               float* __restrict__ out)
{
    int t = threadIdx.x, lane = t & 63, wave = t >> 6;
    float s0 = (t < VS_BLOCKS) ? pclpart[t] : 0.f;   // 64
    float s1 = (t < B_*M_)     ? dmpW[t]    : 0.f;   // 80
    float s2 = 0.f;
    for (int i = t; i < B_*L_; i += 256) {
        float muv = mu[i], lv = logvar[i];
        s2 += -0.5f * (1.f + lv - muv*muv - expf(lv));
    }
    #pragma unroll
    for (int o = 1; o < 64; o <<= 1) {
        s0 += __shfl_xor(s0, o);
        s1 += __shfl_xor(s1, o);
        s2 += __shfl_xor(s2, o);
    }
    __shared__ float sRed[12];
    if (lane == 0) { sRed[wave] = s0; sRed[4+wave] = s1; sRed[8+wave] = s2; }
    __syncthreads();
    if (t == 0) {
        float S0 = sRed[0] + sRed[1] + sRed[2] + sRed[3];
        float S1 = sRed[4] + sRed[5] + sRed[6] + sRed[7];
        float S2 = sRed[8] + sRed[9] + sRed[10] + sRed[11];
        float pcl_to_prim = S0 / (float)(B_ * N_);
        float prim_to_pcl = S1 / (float)(B_ * S_);
        float kld = S2 / (float)B_;
        float prims = pcl_to_prim + prim_to_pcl;
        out[0] = prims + BETA_ * kld;   // total
        out[1] = prims;
        out[2] = 0.f;                   // regs
        out[3] = kld;
    }
}

extern "C" void kernel_launch(void* const* d_in, const int* in_sizes, int n_in,
                              void* d_out, int out_size, void* d_ws, size_t ws_size,
                              hipStream_t stream) {
    const float* ipts    = (const float*)d_in[0];
    const float* trans   = (const float*)d_in[1];
    const float* rot     = (const float*)d_in[2];
    const float* psize   = (const float*)d_in[3];
    const float* shp     = (const float*)d_in[4];
    const float* def     = (const float*)d_in[5];
    const float* probs   = (const float*)d_in[6];
    const float* etas    = (const float*)d_in[7];
    const float* omegas  = (const float*)d_in[8];
    const float* mu      = (const float*)d_in[9];
    const float* logvar  = (const float*)d_in[10];
    float* out = (float*)d_out;

    char* ws = (char*)d_ws;
    float* vpart   = (float*)(ws);                   // B*M*N*4        = 655360
    float* spart   = (float*)(ws + 655360);          // B*M*TILES*S*4  = 1024000
    float* pclpart = (float*)(ws + 1679360);         // 64*4
    float* dmpW    = (float*)(ws + 1679616);         // 80*4
    // all ws buffers are fully written before being read (pure stores,
    // dispatch-boundary coherence) -> no init / memset needed.

    dist_k<<<DIST_BLOCKS, 256, 0, stream>>>(ipts, trans, rot, psize, shp, def,
                                            etas, omegas, vpart, spart);
    mid_k<<<MID_BLOCKS, 256, 0, stream>>>(vpart, spart, probs, pclpart, dmpW);
    final_k<<<1, 256, 0, stream>>>(pclpart, dmpW, mu, logvar, out);
}